// Round 4
// baseline (296.188 us; speedup 1.0000x reference)
//
#include <hip/hip_runtime.h>
#include <math.h>

typedef unsigned int u32;
typedef unsigned long long u64;
typedef unsigned short u16;

constexpr int NB   = 32;     // batch
constexpr int NN   = 50000;  // boxes per image
constexpr int NC   = 10;     // classes
constexpr int KK   = 512;    // PRE_NMS_TOPK
constexpr int MAXD = 100;    // MAX_DETECTIONS
constexpr int CAP  = 4096;   // LDS candidate capacity
constexpr int CH   = 2000;   // rows per transpose chunk (50000 = 25*2000)

// output section offsets (floats)
constexpr int OFF_BOX = 0;
constexpr int OFF_SC  = NB * MAXD * 4;
constexpr int OFF_LB  = OFF_SC + NB * MAXD;
constexpr int OFF_RT  = OFF_LB + NB * MAXD;
constexpr int OFF_TR  = OFF_RT + NB * MAXD * 3;

__device__ __forceinline__ u32 ord_f32(float s) {
  u32 u = __float_as_uint(s);
  return (u & 0x80000000u) ? ~u : (u | 0x80000000u);
}
__device__ __forceinline__ float unord_f32(u32 o) {
  u32 u = (o & 0x80000000u) ? (o & 0x7FFFFFFFu) : ~o;
  return __uint_as_float(u);
}
// key: high 32 = ordered masked score, low 32 = ~idx (ties -> lower idx wins)
__device__ __forceinline__ u64 make_key(float s, u32 i) {
  float sp = (s > 0.01f) ? s : -INFINITY;
  return ((u64)ord_f32(sp) << 32) | (u64)(u32)(~i);
}

// descending bitonic sort of a[0..n) (n = power of 2), nt threads
__device__ inline void bitonic_desc(u64* a, int n, int t, int nt) {
  for (int k = 2; k <= n; k <<= 1) {
    for (int j = k >> 1; j > 0; j >>= 1) {
      for (int i = t; i < n; i += nt) {
        int ixj = i ^ j;
        if (ixj > i) {
          u64 x = a[i], y = a[ixj];
          if (((i & k) == 0) ? (x < y) : (x > y)) { a[i] = y; a[ixj] = x; }
        }
      }
      __syncthreads();
    }
  }
}

// ---------- Kernel A: coalesced transpose to 16-bit ordered keys ----------
__global__ __launch_bounds__(512) void transpose_kernel(
    const float* __restrict__ cls, u16* __restrict__ ord16) {
  const int blk = blockIdx.x;
  const int b = blk / 25, ch = blk % 25;
  const float* src = cls + ((size_t)b * NN + (size_t)ch * CH) * NC;
  __shared__ u16 tile[CH * 11];  // pad 10->11 to break bank conflicts
  const int t = threadIdx.x;
  for (int q = t; q < CH * NC / 4; q += 512) {
    float4 v = ((const float4*)src)[q];
    float arr[4] = {v.x, v.y, v.z, v.w};
    const int e = q * 4;
#pragma unroll
    for (int k = 0; k < 4; ++k) {
      float x = arr[k];
      u16 o = (x > 0.01f) ? (u16)(ord_f32(x) >> 16) : (u16)0;
      int ee = e + k, r = ee / 10, c = ee - r * 10;
      tile[r * 11 + c] = o;
    }
  }
  __syncthreads();
  for (int q = t; q < CH * NC / 4; q += 512) {
    const int c = q / (CH / 4);
    const int r = (q - c * (CH / 4)) * 4;
    ushort4 o;
    o.x = tile[(r + 0) * 11 + c];
    o.y = tile[(r + 1) * 11 + c];
    o.z = tile[(r + 2) * 11 + c];
    o.w = tile[(r + 3) * 11 + c];
    ((ushort4*)ord16)[((size_t)(b * NC + c) * NN + (size_t)ch * CH + r) >> 2] = o;
  }
}

// ---------- Kernel B: exact top-512 per (b,c), coalesced ----------
__global__ __launch_bounds__(512) void select_kernel(
    const u16* __restrict__ ord16, const float* __restrict__ cls,
    int* __restrict__ out_idx, float* __restrict__ out_sc) {
  const int bc = blockIdx.x;
  const int b = bc / NC, c = bc % NC;
  const u16* col = ord16 + (size_t)bc * NN;
  const float* sbase = cls + (size_t)b * NN * NC + c;
  __shared__ u32 hist[4096];
  __shared__ u64 cand[CAP];
  __shared__ u64 sel[KK];
  __shared__ int s_cnt, s_g, s_d, s_ab;
  const int t = threadIdx.x;

  for (int i = t; i < 4096; i += 512) hist[i] = 0;
  __syncthreads();
  // pass 1: 12-bit histogram over the contiguous u16 column
  for (int q = t; q < NN / 8; q += 512) {
    uint4 v = ((const uint4*)col)[q];
    u32 w[4] = {v.x, v.y, v.z, v.w};
#pragma unroll
    for (int k = 0; k < 4; ++k) {
      atomicAdd(&hist[(w[k] & 0xFFFFu) >> 4], 1u);
      atomicAdd(&hist[(w[k] >> 16) >> 4], 1u);
    }
  }
  __syncthreads();
  // suffix-sum over 4096 bins (hist[i] = count of digits >= i)
  for (int s = 1; s < 4096; s <<= 1) {
    u32 add[8];
#pragma unroll
    for (int k = 0; k < 8; ++k) {
      int i = t + k * 512;
      add[k] = (i + s < 4096) ? hist[i + s] : 0u;
    }
    __syncthreads();
#pragma unroll
    for (int k = 0; k < 8; ++k) hist[t + k * 512] += add[k];
    __syncthreads();
  }
#pragma unroll
  for (int k = 0; k < 8; ++k) {
    int i = t + k * 512;
    u32 S = hist[i], Sn = (i == 4095) ? 0u : hist[i + 1];
    if (S >= (u32)KK && Sn < (u32)KK) { s_d = i; s_ab = (int)Sn; }
  }
  if (t == 0) { s_cnt = 0; s_g = 0; }
  __syncthreads();
  const u32 prefix = (u32)s_d;
  int remaining = KK - s_ab;
  // pass 2: collect strictly-greater -> sel, == prefix -> cand (exact keys)
  for (int q = t; q < NN / 8; q += 512) {
    uint4 v = ((const uint4*)col)[q];
    u32 w[4] = {v.x, v.y, v.z, v.w};
#pragma unroll
    for (int k = 0; k < 8; ++k) {
      u32 h = (k & 1) ? (w[k >> 1] >> 16) : (w[k >> 1] & 0xFFFFu);
      u32 hi = h >> 4;
      if (hi >= prefix) {
        int i = q * 8 + k;
        u64 key = make_key(sbase[(size_t)i * NC], (u32)i);
        if (hi > prefix) {
          int p = atomicAdd(&s_g, 1);
          if (p < KK) sel[p] = key;
        } else {
          int p = atomicAdd(&s_cnt, 1);
          if (p < CAP) cand[p] = key;
        }
      }
    }
  }
  __syncthreads();
  int cnt = min(s_cnt, CAP);
  int G = min(s_g, KK);
  // in-LDS 8-bit radix refinement on exact keys
  int shift = 64 - 12 - 8;  // bits below the 12-bit prefix
  while (cnt > 1024 && shift >= 0) {
    if (t < 256) hist[t] = 0;
    __syncthreads();
    for (int i = t; i < cnt; i += 512)
      atomicAdd(&hist[(u32)(cand[i] >> shift) & 255u], 1u);
    __syncthreads();
    for (int s = 1; s < 256; s <<= 1) {
      u32 add = 0;
      if (t < 256 && t + s < 256) add = hist[t + s];
      __syncthreads();
      if (t < 256) hist[t] += add;
      __syncthreads();
    }
    if (t < 256) {
      u32 S = hist[t], Sn = (t == 255) ? 0u : hist[t + 1];
      if (S >= (u32)remaining && Sn < (u32)remaining) { s_d = t; s_ab = (int)Sn; }
    }
    __syncthreads();
    const u32 d2 = (u32)s_d;
    const int above = s_ab;
    u64 mine[8];
    int nm = 0;
    for (int i = t; i < cnt; i += 512) {
      u64 k = cand[i];
      u32 dg = (u32)(k >> shift) & 255u;
      if (dg > d2) {
        int p = atomicAdd(&s_g, 1);
        if (p < KK) sel[p] = k;
      } else if (dg == d2) {
        mine[nm++] = k;
      }
    }
    __syncthreads();
    if (t == 0) s_cnt = 0;
    __syncthreads();
    for (int k = 0; k < nm; ++k) {
      int p = atomicAdd(&s_cnt, 1);
      if (p < CAP) cand[p] = mine[k];
    }
    __syncthreads();
    remaining -= above;
    cnt = min(s_cnt, CAP);
    G = min(s_g, KK);
    shift -= 8;
  }
  int npow = 2;
  while (npow < cnt) npow <<= 1;
  for (int i = cnt + t; i < npow; i += 512) cand[i] = 0;
  __syncthreads();
  bitonic_desc(cand, npow, t, 512);
  for (int r = t; r < remaining; r += 512) sel[G + r] = cand[r];
  __syncthreads();
  bitonic_desc(sel, KK, t, 512);
  {
    u64 k = sel[t];
    out_idx[bc * KK + t] = (int)(~(u32)k);
    out_sc[bc * KK + t] = unord_f32((u32)(k >> 32));
  }
}

// ---------------- Kernel 2: on-demand greedy NMS, one wave per (b,c) -------
// Only rows of KEPT boxes (<=100) are ever computed; suppressed/invalid
// candidates are skipped via ctz on wave-uniform avail bitmask registers.
__global__ __launch_bounds__(64) void nms_kernel(
    const float* __restrict__ boxes, const int* __restrict__ tidx,
    const float* __restrict__ tsc, float* __restrict__ ksc) {
  const int bc = blockIdx.x;
  const int b = bc / NC;
  __shared__ float4 bx4[KK];
  __shared__ float ars[KK];
  __shared__ float scs[KK];
  __shared__ unsigned char keepf[KK];
  const int lane = threadIdx.x;  // 64 threads = 1 wave

  u64 vw[8];  // validity words (wave-uniform)
#pragma unroll
  for (int q = 0; q < 8; ++q) {
    const int j = q * 64 + lane;
    int idx = tidx[bc * KK + j];
    const float4 bx = *(const float4*)(boxes + ((size_t)b * NN + idx) * 4);
    bx4[j] = bx;
    ars[j] = (bx.z - bx.x) * (bx.w - bx.y);
    float sc = tsc[bc * KK + j];
    scs[j] = sc;
    keepf[j] = 0;
    vw[q] = __ballot(sc > 0.01f);
  }
  __syncthreads();

  // lane-held j-side boxes
  float jx1[8], jy1[8], jx2[8], jy2[8], jar[8];
#pragma unroll
  for (int q = 0; q < 8; ++q) {
    float4 bb = bx4[q * 64 + lane];
    jx1[q] = bb.x; jy1[q] = bb.y; jx2[q] = bb.z; jy2[q] = bb.w;
    jar[q] = ars[q * 64 + lane];
  }

  // RN32(inter/uni) > 0.5  <=>  inter/uni > 0.5 + 2^-25 (tie->even = 0.5)
  // sign(inter - C*uni) exact via one f64 fma (50-bit product <= 53 bits)
  const double C = 0x1.000001p-1;

  u64 sup[8] = {0, 0, 0, 0, 0, 0, 0, 0};
  int count = 0;
  bool done = false;
  for (int w = 0; w < 8 && !done; ++w) {
    u64 av = vw[w] & ~sup[w];
    while (av) {
      const int bbit = (int)__builtin_ctzll(av);
      const int i = w * 64 + bbit;
      if (lane == 0) keepf[i] = 1;
      if (++count == MAXD) { done = true; break; }
      const float4 bi = bx4[i];  // wave-uniform broadcast
      const float ai = ars[i];
      // build row i on demand, words w..7 only (columns j in decided range
      // are irrelevant: their keep decisions are already made)
      for (int q = w; q < 8; ++q) {
        float ix1 = fmaxf(bi.x, jx1[q]);
        float iy1 = fmaxf(bi.y, jy1[q]);
        float ix2 = fminf(bi.z, jx2[q]);
        float iy2 = fminf(bi.w, jy2[q]);
        float iw = fmaxf(ix2 - ix1, 0.0f);
        float ih = fmaxf(iy2 - iy1, 0.0f);
        float inter = iw * ih;
        float uni = ai + jar[q] - inter;
        bool s = (uni > 0.0f) && (fma(-C, (double)uni, (double)inter) > 0.0);
        sup[q] |= __ballot(s);
      }
      const u64 mask_gt = (bbit == 63) ? 0ull : (~0ull << (bbit + 1));
      av = vw[w] & ~sup[w] & mask_gt;
    }
  }
  __syncthreads();
#pragma unroll
  for (int q = 0; q < 8; ++q) {
    const int j = q * 64 + lane;
    ksc[bc * KK + j] = keepf[j] ? scs[j] : -INFINITY;
  }
}

// ---------------- Kernel 3: per-image top-100 + gather ----------------
__global__ __launch_bounds__(512) void final_kernel(
    const float* __restrict__ boxes, const float* __restrict__ rot,
    const float* __restrict__ trans, const int* __restrict__ tidx,
    const float* __restrict__ ksc, float* __restrict__ out) {
  const int b = blockIdx.x;
  __shared__ u64 ck[1024];
  __shared__ int cnt;
  const int t = threadIdx.x;
  if (t == 0) cnt = 0;
  __syncthreads();
  for (int j = t; j < NC * KK; j += 512) {
    float s = ksc[b * NC * KK + j];
    if (s != -INFINITY) {
      int p = atomicAdd(&cnt, 1);
      if (p < 1024) ck[p] = ((u64)ord_f32(s) << 32) | (u64)(u32)(~(u32)j);
    }
  }
  __syncthreads();
  const int n = min(cnt, 1024);
  int npow = 128;
  while (npow < n) npow <<= 1;
  for (int i = n + t; i < npow; i += 512) ck[i] = 0;
  __syncthreads();
  bitonic_desc(ck, npow, t, 512);

  if (t < MAXD) {
    float b0 = -1.f, b1 = -1.f, b2 = -1.f, b3 = -1.f;
    float os = -1.f, ol = -1.f;
    float r0 = -1.f, r1 = -1.f, r2 = -1.f;
    float t0 = -1.f, t1 = -1.f, t2 = -1.f;
    if (t < n) {
      u64 k = ck[t];
      int j = (int)(~(u32)k);
      int c = j >> 9, slot = j & (KK - 1);
      int idx = tidx[(b * NC + c) * KK + slot];
      os = unord_f32((u32)(k >> 32));
      ol = (float)c;
      const float4 bx = *(const float4*)(boxes + ((size_t)b * NN + idx) * 4);
      b0 = bx.x; b1 = bx.y; b2 = bx.z; b3 = bx.w;
      const float* rp = rot + ((size_t)b * NN + idx) * 3;
      r0 = rp[0]; r1 = rp[1]; r2 = rp[2];
      const float* tp = trans + ((size_t)b * NN + idx) * 3;
      t0 = tp[0]; t1 = tp[1]; t2 = tp[2];
    }
    const int o = b * MAXD + t;
    out[OFF_BOX + (size_t)o * 4 + 0] = b0;
    out[OFF_BOX + (size_t)o * 4 + 1] = b1;
    out[OFF_BOX + (size_t)o * 4 + 2] = b2;
    out[OFF_BOX + (size_t)o * 4 + 3] = b3;
    out[OFF_SC + o] = os;
    out[OFF_LB + o] = ol;
    out[OFF_RT + (size_t)o * 3 + 0] = r0;
    out[OFF_RT + (size_t)o * 3 + 1] = r1;
    out[OFF_RT + (size_t)o * 3 + 2] = r2;
    out[OFF_TR + (size_t)o * 3 + 0] = t0;
    out[OFF_TR + (size_t)o * 3 + 1] = t1;
    out[OFF_TR + (size_t)o * 3 + 2] = t2;
  }
}

extern "C" void kernel_launch(void* const* d_in, const int* in_sizes, int n_in,
                              void* d_out, int out_size, void* d_ws, size_t ws_size,
                              hipStream_t stream) {
  const float* boxes = (const float*)d_in[0];
  const float* cls   = (const float*)d_in[1];
  const float* rot   = (const float*)d_in[2];
  const float* trans = (const float*)d_in[3];
  float* out = (float*)d_out;

  u16* ord16 = (u16*)d_ws;                             // 32 MB
  int* tidx  = (int*)(ord16 + (size_t)NB * NC * NN);
  float* tsc = (float*)(tidx + NB * NC * KK);
  float* ksc = tsc + NB * NC * KK;

  transpose_kernel<<<NB * 25, 512, 0, stream>>>(cls, ord16);
  select_kernel<<<NB * NC, 512, 0, stream>>>(ord16, cls, tidx, tsc);
  nms_kernel<<<NB * NC, 64, 0, stream>>>(boxes, tidx, tsc, ksc);
  final_kernel<<<NB, 512, 0, stream>>>(boxes, rot, trans, tidx, ksc, out);
}

// Round 5
// 184.540 us; speedup vs baseline: 1.6050x; 1.6050x over previous
//
#include <hip/hip_runtime.h>
#include <math.h>

typedef unsigned int u32;
typedef unsigned long long u64;
typedef unsigned short u16;

constexpr int NB   = 32;     // batch
constexpr int NN   = 50000;  // boxes per image
constexpr int NC   = 10;     // classes
constexpr int KK   = 512;    // PRE_NMS_TOPK
constexpr int MAXD = 100;    // MAX_DETECTIONS
constexpr int CAP  = 4096;   // LDS candidate capacity
constexpr int CH   = 2000;   // rows per transpose chunk (50000 = 25*2000)

// output section offsets (floats)
constexpr int OFF_BOX = 0;
constexpr int OFF_SC  = NB * MAXD * 4;
constexpr int OFF_LB  = OFF_SC + NB * MAXD;
constexpr int OFF_RT  = OFF_LB + NB * MAXD;
constexpr int OFF_TR  = OFF_RT + NB * MAXD * 3;

__device__ __forceinline__ u32 ord_f32(float s) {
  u32 u = __float_as_uint(s);
  return (u & 0x80000000u) ? ~u : (u | 0x80000000u);
}
__device__ __forceinline__ float unord_f32(u32 o) {
  u32 u = (o & 0x80000000u) ? (o & 0x7FFFFFFFu) : ~o;
  return __uint_as_float(u);
}
// key: high 32 = ordered masked score, low 32 = ~idx (ties -> lower idx wins)
__device__ __forceinline__ u64 make_key(float s, u32 i) {
  float sp = (s > 0.01f) ? s : -INFINITY;
  return ((u64)ord_f32(sp) << 32) | (u64)(u32)(~i);
}

// descending bitonic sort of a[0..n) (n = power of 2), nt threads
__device__ inline void bitonic_desc(u64* a, int n, int t, int nt) {
  for (int k = 2; k <= n; k <<= 1) {
    for (int j = k >> 1; j > 0; j >>= 1) {
      for (int i = t; i < n; i += nt) {
        int ixj = i ^ j;
        if (ixj > i) {
          u64 x = a[i], y = a[ixj];
          if (((i & k) == 0) ? (x < y) : (x > y)) { a[i] = y; a[ixj] = x; }
        }
      }
      __syncthreads();
    }
  }
}

// ---------- Kernel A: coalesced transpose to 16-bit ordered keys ----------
__global__ __launch_bounds__(512) void transpose_kernel(
    const float* __restrict__ cls, u16* __restrict__ ord16) {
  const int blk = blockIdx.x;
  const int b = blk / 25, ch = blk % 25;
  const float* src = cls + ((size_t)b * NN + (size_t)ch * CH) * NC;
  __shared__ u16 tile[CH * 11];  // pad 10->11 to break bank conflicts
  const int t = threadIdx.x;
  for (int q = t; q < CH * NC / 4; q += 512) {
    float4 v = ((const float4*)src)[q];
    float arr[4] = {v.x, v.y, v.z, v.w};
    const int e = q * 4;
#pragma unroll
    for (int k = 0; k < 4; ++k) {
      float x = arr[k];
      u16 o = (x > 0.01f) ? (u16)(ord_f32(x) >> 16) : (u16)0;
      int ee = e + k, r = ee / 10, c = ee - r * 10;
      tile[r * 11 + c] = o;
    }
  }
  __syncthreads();
  for (int q = t; q < CH * NC / 4; q += 512) {
    const int c = q / (CH / 4);
    const int r = (q - c * (CH / 4)) * 4;
    ushort4 o;
    o.x = tile[(r + 0) * 11 + c];
    o.y = tile[(r + 1) * 11 + c];
    o.z = tile[(r + 2) * 11 + c];
    o.w = tile[(r + 3) * 11 + c];
    ((ushort4*)ord16)[((size_t)(b * NC + c) * NN + (size_t)ch * CH + r) >> 2] = o;
  }
}

// ---------- Kernel B: exact top-512 per (b,c), coalesced ----------
__global__ __launch_bounds__(512) void select_kernel(
    const u16* __restrict__ ord16, const float* __restrict__ cls,
    int* __restrict__ out_idx, float* __restrict__ out_sc) {
  const int bc = blockIdx.x;
  const int b = bc / NC, c = bc % NC;
  const u16* col = ord16 + (size_t)bc * NN;
  const float* sbase = cls + (size_t)b * NN * NC + c;
  __shared__ u32 hist[4096];
  __shared__ u64 cand[CAP];
  __shared__ u64 sel[KK];
  __shared__ int s_cnt, s_g, s_d, s_ab;
  const int t = threadIdx.x;

  for (int i = t; i < 4096; i += 512) hist[i] = 0;
  __syncthreads();
  // pass 1: 12-bit histogram over the contiguous u16 column
  for (int q = t; q < NN / 8; q += 512) {
    uint4 v = ((const uint4*)col)[q];
    u32 w[4] = {v.x, v.y, v.z, v.w};
#pragma unroll
    for (int k = 0; k < 4; ++k) {
      atomicAdd(&hist[(w[k] & 0xFFFFu) >> 4], 1u);
      atomicAdd(&hist[(w[k] >> 16) >> 4], 1u);
    }
  }
  __syncthreads();
  // suffix-sum over 4096 bins (hist[i] = count of digits >= i)
  for (int s = 1; s < 4096; s <<= 1) {
    u32 add[8];
#pragma unroll
    for (int k = 0; k < 8; ++k) {
      int i = t + k * 512;
      add[k] = (i + s < 4096) ? hist[i + s] : 0u;
    }
    __syncthreads();
#pragma unroll
    for (int k = 0; k < 8; ++k) hist[t + k * 512] += add[k];
    __syncthreads();
  }
#pragma unroll
  for (int k = 0; k < 8; ++k) {
    int i = t + k * 512;
    u32 S = hist[i], Sn = (i == 4095) ? 0u : hist[i + 1];
    if (S >= (u32)KK && Sn < (u32)KK) { s_d = i; s_ab = (int)Sn; }
  }
  if (t == 0) { s_cnt = 0; s_g = 0; }
  __syncthreads();
  const u32 prefix = (u32)s_d;
  int remaining = KK - s_ab;
  // pass 2: collect strictly-greater -> sel, == prefix -> cand (exact keys)
  for (int q = t; q < NN / 8; q += 512) {
    uint4 v = ((const uint4*)col)[q];
    u32 w[4] = {v.x, v.y, v.z, v.w};
#pragma unroll
    for (int k = 0; k < 8; ++k) {
      u32 h = (k & 1) ? (w[k >> 1] >> 16) : (w[k >> 1] & 0xFFFFu);
      u32 hi = h >> 4;
      if (hi >= prefix) {
        int i = q * 8 + k;
        u64 key = make_key(sbase[(size_t)i * NC], (u32)i);
        if (hi > prefix) {
          int p = atomicAdd(&s_g, 1);
          if (p < KK) sel[p] = key;
        } else {
          int p = atomicAdd(&s_cnt, 1);
          if (p < CAP) cand[p] = key;
        }
      }
    }
  }
  __syncthreads();
  int cnt = min(s_cnt, CAP);
  int G = min(s_g, KK);
  // in-LDS 8-bit radix refinement on exact keys
  int shift = 64 - 12 - 8;  // bits below the 12-bit prefix
  while (cnt > 1024 && shift >= 0) {
    if (t < 256) hist[t] = 0;
    __syncthreads();
    for (int i = t; i < cnt; i += 512)
      atomicAdd(&hist[(u32)(cand[i] >> shift) & 255u], 1u);
    __syncthreads();
    for (int s = 1; s < 256; s <<= 1) {
      u32 add = 0;
      if (t < 256 && t + s < 256) add = hist[t + s];
      __syncthreads();
      if (t < 256) hist[t] += add;
      __syncthreads();
    }
    if (t < 256) {
      u32 S = hist[t], Sn = (t == 255) ? 0u : hist[t + 1];
      if (S >= (u32)remaining && Sn < (u32)remaining) { s_d = t; s_ab = (int)Sn; }
    }
    __syncthreads();
    const u32 d2 = (u32)s_d;
    const int above = s_ab;
    u64 mine[8];
    int nm = 0;
    for (int i = t; i < cnt; i += 512) {
      u64 k = cand[i];
      u32 dg = (u32)(k >> shift) & 255u;
      if (dg > d2) {
        int p = atomicAdd(&s_g, 1);
        if (p < KK) sel[p] = k;
      } else if (dg == d2) {
        mine[nm++] = k;
      }
    }
    __syncthreads();
    if (t == 0) s_cnt = 0;
    __syncthreads();
    for (int k = 0; k < nm; ++k) {
      int p = atomicAdd(&s_cnt, 1);
      if (p < CAP) cand[p] = mine[k];
    }
    __syncthreads();
    remaining -= above;
    cnt = min(s_cnt, CAP);
    G = min(s_g, KK);
    shift -= 8;
  }
  int npow = 2;
  while (npow < cnt) npow <<= 1;
  for (int i = cnt + t; i < npow; i += 512) cand[i] = 0;
  __syncthreads();
  bitonic_desc(cand, npow, t, 512);
  for (int r = t; r < remaining; r += 512) sel[G + r] = cand[r];
  __syncthreads();
  bitonic_desc(sel, KK, t, 512);
  {
    u64 k = sel[t];
    out_idx[bc * KK + t] = (int)(~(u32)k);
    out_sc[bc * KK + t] = unord_f32((u32)(k >> 32));
  }
}

// ------- Kernel 2: on-demand greedy NMS, one wave per (b,c), 2 per block ----
// All mask state in wave-uniform registers (ballot -> SGPR); static indexing
// only (rule #20); rows built on demand only for KEPT boxes (<=100).
__global__ __launch_bounds__(128) void nms_kernel(
    const float* __restrict__ boxes, const int* __restrict__ tidx,
    const float* __restrict__ tsc, float* __restrict__ ksc) {
  const int wv = threadIdx.x >> 6;              // 0..1: problem within block
  const int lane = threadIdx.x & 63;
  const int bc = blockIdx.x * 2 + wv;           // 320 problems, 160 blocks
  const int b = bc / NC;
  __shared__ float4 bx4[2][KK];                 // 16 KiB
  __shared__ float ars[2][KK];                  // 4 KiB

  float jx1[8], jy1[8], jx2[8], jy2[8], jar[8], jsc[8];
  u64 vw[8], sup[8], kw[8];
#pragma unroll
  for (int q = 0; q < 8; ++q) {
    const int j = q * 64 + lane;
    int idx = tidx[bc * KK + j];
    const float4 bx = *(const float4*)(boxes + ((size_t)b * NN + idx) * 4);
    float ar = (bx.z - bx.x) * (bx.w - bx.y);
    bx4[wv][j] = bx;
    ars[wv][j] = ar;
    jx1[q] = bx.x; jy1[q] = bx.y; jx2[q] = bx.z; jy2[q] = bx.w;
    jar[q] = ar;
    float sc = tsc[bc * KK + j];
    jsc[q] = sc;
    vw[q] = __ballot(sc > 0.01f);
    sup[q] = 0;
    kw[q] = 0;
  }
  // same-wave LDS write->read: compiler inserts lgkmcnt waits; no barrier
  // needed (the two waves touch disjoint LDS halves).

  // RN32(inter/uni) > 0.5  <=>  inter/uni > 0.5 + 2^-25 (tie->even = 0.5)
  // sign(inter - C*uni) exact via one f64 fma (50-bit product <= 53 bits)
  const double C = 0x1.000001p-1;

  int count = 0;
  bool done = false;
#pragma unroll
  for (int w = 0; w < 8; ++w) {  // w is compile-time in each unrolled copy
    if (!done) {
      u64 av = vw[w] & ~sup[w];
      while (av) {
        const int bbit = (int)__builtin_ctzll(av);
        const int i = w * 64 + bbit;
        kw[w] |= 1ull << bbit;
        if (++count == MAXD) { done = true; break; }
        const float4 bi = bx4[wv][i];  // wave-uniform broadcast read
        const float ai = ars[wv][i];
#pragma unroll
        for (int q = 0; q < 8; ++q) {
          if (q >= w) {  // compile-time guard: only undecided words
            float ix1 = fmaxf(bi.x, jx1[q]);
            float iy1 = fmaxf(bi.y, jy1[q]);
            float ix2 = fminf(bi.z, jx2[q]);
            float iy2 = fminf(bi.w, jy2[q]);
            float iw = fmaxf(ix2 - ix1, 0.0f);
            float ih = fmaxf(iy2 - iy1, 0.0f);
            float inter = iw * ih;
            float uni = ai + jar[q] - inter;
            bool s = (uni > 0.0f) && (fma(-C, (double)uni, (double)inter) > 0.0);
            sup[q] |= __ballot(s);
          }
        }
        const u64 mask_gt = (bbit == 63) ? 0ull : (~0ull << (bbit + 1));
        av = vw[w] & ~sup[w] & mask_gt;
      }
    }
  }

#pragma unroll
  for (int q = 0; q < 8; ++q) {
    const int j = q * 64 + lane;
    ksc[bc * KK + j] = ((kw[q] >> lane) & 1ull) ? jsc[q] : -INFINITY;
  }
}

// ---------------- Kernel 3: per-image top-100 + gather ----------------
__global__ __launch_bounds__(512) void final_kernel(
    const float* __restrict__ boxes, const float* __restrict__ rot,
    const float* __restrict__ trans, const int* __restrict__ tidx,
    const float* __restrict__ ksc, float* __restrict__ out) {
  const int b = blockIdx.x;
  __shared__ u64 ck[1024];
  __shared__ int cnt;
  const int t = threadIdx.x;
  if (t == 0) cnt = 0;
  __syncthreads();
  for (int j = t; j < NC * KK; j += 512) {
    float s = ksc[b * NC * KK + j];
    if (s != -INFINITY) {
      int p = atomicAdd(&cnt, 1);
      if (p < 1024) ck[p] = ((u64)ord_f32(s) << 32) | (u64)(u32)(~(u32)j);
    }
  }
  __syncthreads();
  const int n = min(cnt, 1024);
  int npow = 128;
  while (npow < n) npow <<= 1;
  for (int i = n + t; i < npow; i += 512) ck[i] = 0;
  __syncthreads();
  bitonic_desc(ck, npow, t, 512);

  if (t < MAXD) {
    float b0 = -1.f, b1 = -1.f, b2 = -1.f, b3 = -1.f;
    float os = -1.f, ol = -1.f;
    float r0 = -1.f, r1 = -1.f, r2 = -1.f;
    float t0 = -1.f, t1 = -1.f, t2 = -1.f;
    if (t < n) {
      u64 k = ck[t];
      int j = (int)(~(u32)k);
      int c = j >> 9, slot = j & (KK - 1);
      int idx = tidx[(b * NC + c) * KK + slot];
      os = unord_f32((u32)(k >> 32));
      ol = (float)c;
      const float4 bx = *(const float4*)(boxes + ((size_t)b * NN + idx) * 4);
      b0 = bx.x; b1 = bx.y; b2 = bx.z; b3 = bx.w;
      const float* rp = rot + ((size_t)b * NN + idx) * 3;
      r0 = rp[0]; r1 = rp[1]; r2 = rp[2];
      const float* tp = trans + ((size_t)b * NN + idx) * 3;
      t0 = tp[0]; t1 = tp[1]; t2 = tp[2];
    }
    const int o = b * MAXD + t;
    out[OFF_BOX + (size_t)o * 4 + 0] = b0;
    out[OFF_BOX + (size_t)o * 4 + 1] = b1;
    out[OFF_BOX + (size_t)o * 4 + 2] = b2;
    out[OFF_BOX + (size_t)o * 4 + 3] = b3;
    out[OFF_SC + o] = os;
    out[OFF_LB + o] = ol;
    out[OFF_RT + (size_t)o * 3 + 0] = r0;
    out[OFF_RT + (size_t)o * 3 + 1] = r1;
    out[OFF_RT + (size_t)o * 3 + 2] = r2;
    out[OFF_TR + (size_t)o * 3 + 0] = t0;
    out[OFF_TR + (size_t)o * 3 + 1] = t1;
    out[OFF_TR + (size_t)o * 3 + 2] = t2;
  }
}

extern "C" void kernel_launch(void* const* d_in, const int* in_sizes, int n_in,
                              void* d_out, int out_size, void* d_ws, size_t ws_size,
                              hipStream_t stream) {
  const float* boxes = (const float*)d_in[0];
  const float* cls   = (const float*)d_in[1];
  const float* rot   = (const float*)d_in[2];
  const float* trans = (const float*)d_in[3];
  float* out = (float*)d_out;

  u16* ord16 = (u16*)d_ws;                             // 32 MB
  int* tidx  = (int*)(ord16 + (size_t)NB * NC * NN);
  float* tsc = (float*)(tidx + NB * NC * KK);
  float* ksc = tsc + NB * NC * KK;

  transpose_kernel<<<NB * 25, 512, 0, stream>>>(cls, ord16);
  select_kernel<<<NB * NC, 512, 0, stream>>>(ord16, cls, tidx, tsc);
  nms_kernel<<<NB * NC / 2, 128, 0, stream>>>(boxes, tidx, tsc, ksc);
  final_kernel<<<NB, 512, 0, stream>>>(boxes, rot, trans, tidx, ksc, out);
}

// Round 6
// 161.073 us; speedup vs baseline: 1.8388x; 1.1457x over previous
//
#include <hip/hip_runtime.h>
#include <math.h>

typedef unsigned int u32;
typedef unsigned long long u64;
typedef unsigned short u16;

constexpr int NB   = 32;     // batch
constexpr int NN   = 50000;  // boxes per image
constexpr int NC   = 10;     // classes
constexpr int KK   = 512;    // PRE_NMS_TOPK
constexpr int MAXD = 100;    // MAX_DETECTIONS
constexpr int CAP  = 4096;   // 12-bit tie-bucket capacity (expected ~3125)
constexpr int TCAP = 1024;   // 16-bit tie-bucket capacity (expected ~200)
constexpr int CH   = 2000;   // rows per transpose chunk (50000 = 25*2000)

// output section offsets (floats)
constexpr int OFF_BOX = 0;
constexpr int OFF_SC  = NB * MAXD * 4;
constexpr int OFF_LB  = OFF_SC + NB * MAXD;
constexpr int OFF_RT  = OFF_LB + NB * MAXD;
constexpr int OFF_TR  = OFF_RT + NB * MAXD * 3;

__device__ __forceinline__ u32 ord_f32(float s) {
  u32 u = __float_as_uint(s);
  return (u & 0x80000000u) ? ~u : (u | 0x80000000u);
}
__device__ __forceinline__ float unord_f32(u32 o) {
  u32 u = (o & 0x80000000u) ? (o & 0x7FFFFFFFu) : ~o;
  return __uint_as_float(u);
}
// key: high 32 = ordered masked score, low 32 = ~idx (ties -> lower idx wins)
__device__ __forceinline__ u64 make_key(float s, u32 i) {
  float sp = (s > 0.01f) ? s : -INFINITY;
  return ((u64)ord_f32(sp) << 32) | (u64)(u32)(~i);
}

// descending bitonic sort of a[0..n) (n = power of 2), nt threads
__device__ inline void bitonic_desc(u64* a, int n, int t, int nt) {
  for (int k = 2; k <= n; k <<= 1) {
    for (int j = k >> 1; j > 0; j >>= 1) {
      for (int i = t; i < n; i += nt) {
        int ixj = i ^ j;
        if (ixj > i) {
          u64 x = a[i], y = a[ixj];
          if (((i & k) == 0) ? (x < y) : (x > y)) { a[i] = y; a[ixj] = x; }
        }
      }
      __syncthreads();
    }
  }
}

// ---------- Kernel A: coalesced transpose to 16-bit ordered keys ----------
__global__ __launch_bounds__(512) void transpose_kernel(
    const float* __restrict__ cls, u16* __restrict__ ord16) {
  const int blk = blockIdx.x;
  const int b = blk / 25, ch = blk % 25;
  const float* src = cls + ((size_t)b * NN + (size_t)ch * CH) * NC;
  __shared__ u16 tile[CH * 11];  // pad 10->11 to break bank conflicts
  const int t = threadIdx.x;
  for (int q = t; q < CH * NC / 4; q += 512) {
    float4 v = ((const float4*)src)[q];
    float arr[4] = {v.x, v.y, v.z, v.w};
    const int e = q * 4;
#pragma unroll
    for (int k = 0; k < 4; ++k) {
      float x = arr[k];
      u16 o = (x > 0.01f) ? (u16)(ord_f32(x) >> 16) : (u16)0;
      int ee = e + k, r = ee / 10, c = ee - r * 10;
      tile[r * 11 + c] = o;
    }
  }
  __syncthreads();
  for (int q = t; q < CH * NC / 4; q += 512) {
    const int c = q / (CH / 4);
    const int r = (q - c * (CH / 4)) * 4;
    ushort4 o;
    o.x = tile[(r + 0) * 11 + c];
    o.y = tile[(r + 1) * 11 + c];
    o.z = tile[(r + 2) * 11 + c];
    o.w = tile[(r + 3) * 11 + c];
    ((ushort4*)ord16)[((size_t)(b * NC + c) * NN + (size_t)ch * CH + r) >> 2] = o;
  }
}

// ---------- Kernel B: exact top-512 per (b,c), two-level digest ----------
__global__ __launch_bounds__(512) void select_kernel(
    const u16* __restrict__ ord16, const float* __restrict__ cls,
    int* __restrict__ out_idx, float* __restrict__ out_sc) {
  const int bc = blockIdx.x;
  const int b = bc / NC, c = bc % NC;
  const u16* col = ord16 + (size_t)bc * NN;
  const float* sbase = cls + (size_t)b * NN * NC + c;
  __shared__ __align__(16) u32 hist[4096];  // 16 KiB; aliased as tie[] later
  __shared__ u32 cand[CAP];                 // 16 KiB packed (low4<<16)|idx
  __shared__ u64 sel[KK];                   // 4 KiB
  __shared__ int s_cnt, s_g, s_t, s_d, s_ab;
  const int t = threadIdx.x;

  for (int i = t; i < 4096; i += 512) hist[i] = 0;
  __syncthreads();
  // pass 1: 12-bit histogram over the contiguous u16 column
  for (int q = t; q < NN / 8; q += 512) {
    uint4 v = ((const uint4*)col)[q];
    u32 w[4] = {v.x, v.y, v.z, v.w};
#pragma unroll
    for (int k = 0; k < 4; ++k) {
      atomicAdd(&hist[(w[k] & 0xFFFFu) >> 4], 1u);
      atomicAdd(&hist[(w[k] >> 16) >> 4], 1u);
    }
  }
  __syncthreads();
  // suffix-sum over 4096 bins (hist[i] = count of digits >= i)
  for (int s = 1; s < 4096; s <<= 1) {
    u32 add[8];
#pragma unroll
    for (int k = 0; k < 8; ++k) {
      int i = t + k * 512;
      add[k] = (i + s < 4096) ? hist[i + s] : 0u;
    }
    __syncthreads();
#pragma unroll
    for (int k = 0; k < 8; ++k) hist[t + k * 512] += add[k];
    __syncthreads();
  }
#pragma unroll
  for (int k = 0; k < 8; ++k) {
    int i = t + k * 512;
    u32 S = hist[i], Sn = (i == 4095) ? 0u : hist[i + 1];
    if (S >= (u32)KK && Sn < (u32)KK) { s_d = i; s_ab = (int)Sn; }
  }
  if (t == 0) { s_cnt = 0; s_g = 0; s_t = 0; }
  __syncthreads();
  const u32 prefix12 = (u32)s_d;
  const int above12 = s_ab;          // count of digest>>4 > prefix12
  const int remaining12 = KK - above12;
  if (t < 16) hist[t] = 0;           // 4096-suffix values now dead; reuse 0..15
  __syncthreads();

  // pass 2: digest>prefix12 -> gather exact key into sel;
  //         digest==prefix12 -> pack (low4,idx) into cand + 16-bin histogram
  for (int q = t; q < NN / 8; q += 512) {
    uint4 v = ((const uint4*)col)[q];
    u32 w[4] = {v.x, v.y, v.z, v.w};
#pragma unroll
    for (int k = 0; k < 8; ++k) {
      u32 dg = (k & 1) ? (w[k >> 1] >> 16) : (w[k >> 1] & 0xFFFFu);
      u32 hi = dg >> 4;
      if (hi >= prefix12) {
        u32 i = (u32)(q * 8 + k);
        if (hi > prefix12) {
          int p = atomicAdd(&s_g, 1);
          if (p < KK) sel[p] = make_key(sbase[(size_t)i * NC], i);
        } else {
          atomicAdd(&hist[dg & 15u], 1u);
          int p = atomicAdd(&s_cnt, 1);
          if (p < CAP) cand[p] = ((dg & 15u) << 16) | i;  // idx < 65536
        }
      }
    }
  }
  __syncthreads();
  // 16-bin suffix scan + pick low4 threshold (serial in thread 0, 16 iters)
  if (t == 0) {
    u32 run = 0;
    int d4 = 0, ab4 = 0;
    for (int i = 15; i >= 0; --i) {
      u32 nxt = run + hist[i];
      if (nxt >= (u32)remaining12 && run < (u32)remaining12) { d4 = i; ab4 = (int)run; }
      run = nxt;
    }
    s_d = d4;
    s_ab = ab4;
    s_t = 0;
  }
  __syncthreads();
  const u32 p4 = (u32)s_d;
  const int above4 = s_ab;                 // low4 > p4 count (joins sel)
  const int remaining4 = remaining12 - above4;
  const int cnt = min(s_cnt, CAP);
  u64* tie = reinterpret_cast<u64*>(hist);  // 16 KiB alias, holds TCAP u64
  // partition the 12-bit bucket using the 4 extra digest bits
  for (int i = t; i < cnt; i += 512) {
    u32 pk = cand[i];
    u32 l4 = pk >> 16;
    u32 idx = pk & 0xFFFFu;
    if (l4 > p4) {
      int p = atomicAdd(&s_g, 1);
      if (p < KK) sel[p] = make_key(sbase[(size_t)idx * NC], idx);
    } else if (l4 == p4) {
      int p = atomicAdd(&s_t, 1);
      if (p < TCAP) tie[p] = make_key(sbase[(size_t)idx * NC], idx);
    }
  }
  __syncthreads();
  const int G = min(s_g, KK);              // = above12 + above4 = 512 - remaining4
  const int tn = min(s_t, TCAP);
  int npow = 2;
  while (npow < tn) npow <<= 1;
  for (int i = tn + t; i < npow; i += 512) tie[i] = 0;
  __syncthreads();
  bitonic_desc(tie, npow, t, 512);
  for (int r = t; r < remaining4; r += 512) sel[G + r] = tie[r];
  __syncthreads();
  bitonic_desc(sel, KK, t, 512);
  {
    u64 k = sel[t];
    out_idx[bc * KK + t] = (int)(~(u32)k);
    out_sc[bc * KK + t] = unord_f32((u32)(k >> 32));
  }
}

// ------- Kernel 2: on-demand greedy NMS, one wave per (b,c), 2 per block ----
__global__ __launch_bounds__(128) void nms_kernel(
    const float* __restrict__ boxes, const int* __restrict__ tidx,
    const float* __restrict__ tsc, float* __restrict__ ksc) {
  const int wv = threadIdx.x >> 6;
  const int lane = threadIdx.x & 63;
  const int bc = blockIdx.x * 2 + wv;
  const int b = bc / NC;
  __shared__ float4 bx4[2][KK];
  __shared__ float ars[2][KK];

  float jx1[8], jy1[8], jx2[8], jy2[8], jar[8], jsc[8];
  u64 vw[8], sup[8], kw[8];
#pragma unroll
  for (int q = 0; q < 8; ++q) {
    const int j = q * 64 + lane;
    int idx = tidx[bc * KK + j];
    const float4 bx = *(const float4*)(boxes + ((size_t)b * NN + idx) * 4);
    float ar = (bx.z - bx.x) * (bx.w - bx.y);
    bx4[wv][j] = bx;
    ars[wv][j] = ar;
    jx1[q] = bx.x; jy1[q] = bx.y; jx2[q] = bx.z; jy2[q] = bx.w;
    jar[q] = ar;
    float sc = tsc[bc * KK + j];
    jsc[q] = sc;
    vw[q] = __ballot(sc > 0.01f);
    sup[q] = 0;
    kw[q] = 0;
  }

  // RN32(inter/uni) > 0.5  <=>  inter/uni > 0.5 + 2^-25 (tie->even = 0.5)
  const double C = 0x1.000001p-1;

  int count = 0;
  bool done = false;
#pragma unroll
  for (int w = 0; w < 8; ++w) {
    if (!done) {
      u64 av = vw[w] & ~sup[w];
      while (av) {
        const int bbit = (int)__builtin_ctzll(av);
        const int i = w * 64 + bbit;
        kw[w] |= 1ull << bbit;
        if (++count == MAXD) { done = true; break; }
        const float4 bi = bx4[wv][i];
        const float ai = ars[wv][i];
#pragma unroll
        for (int q = 0; q < 8; ++q) {
          if (q >= w) {
            float ix1 = fmaxf(bi.x, jx1[q]);
            float iy1 = fmaxf(bi.y, jy1[q]);
            float ix2 = fminf(bi.z, jx2[q]);
            float iy2 = fminf(bi.w, jy2[q]);
            float iw = fmaxf(ix2 - ix1, 0.0f);
            float ih = fmaxf(iy2 - iy1, 0.0f);
            float inter = iw * ih;
            float uni = ai + jar[q] - inter;
            bool s = (uni > 0.0f) && (fma(-C, (double)uni, (double)inter) > 0.0);
            sup[q] |= __ballot(s);
          }
        }
        const u64 mask_gt = (bbit == 63) ? 0ull : (~0ull << (bbit + 1));
        av = vw[w] & ~sup[w] & mask_gt;
      }
    }
  }

#pragma unroll
  for (int q = 0; q < 8; ++q) {
    const int j = q * 64 + lane;
    ksc[bc * KK + j] = ((kw[q] >> lane) & 1ull) ? jsc[q] : -INFINITY;
  }
}

// ---------------- Kernel 3: per-image top-100 + gather ----------------
__global__ __launch_bounds__(512) void final_kernel(
    const float* __restrict__ boxes, const float* __restrict__ rot,
    const float* __restrict__ trans, const int* __restrict__ tidx,
    const float* __restrict__ ksc, float* __restrict__ out) {
  const int b = blockIdx.x;
  __shared__ u64 ck[1024];
  __shared__ int cnt;
  const int t = threadIdx.x;
  if (t == 0) cnt = 0;
  __syncthreads();
  for (int j = t; j < NC * KK; j += 512) {
    float s = ksc[b * NC * KK + j];
    if (s != -INFINITY) {
      int p = atomicAdd(&cnt, 1);
      if (p < 1024) ck[p] = ((u64)ord_f32(s) << 32) | (u64)(u32)(~(u32)j);
    }
  }
  __syncthreads();
  const int n = min(cnt, 1024);
  int npow = 128;
  while (npow < n) npow <<= 1;
  for (int i = n + t; i < npow; i += 512) ck[i] = 0;
  __syncthreads();
  bitonic_desc(ck, npow, t, 512);

  if (t < MAXD) {
    float b0 = -1.f, b1 = -1.f, b2 = -1.f, b3 = -1.f;
    float os = -1.f, ol = -1.f;
    float r0 = -1.f, r1 = -1.f, r2 = -1.f;
    float t0 = -1.f, t1 = -1.f, t2 = -1.f;
    if (t < n) {
      u64 k = ck[t];
      int j = (int)(~(u32)k);
      int c = j >> 9, slot = j & (KK - 1);
      int idx = tidx[(b * NC + c) * KK + slot];
      os = unord_f32((u32)(k >> 32));
      ol = (float)c;
      const float4 bx = *(const float4*)(boxes + ((size_t)b * NN + idx) * 4);
      b0 = bx.x; b1 = bx.y; b2 = bx.z; b3 = bx.w;
      const float* rp = rot + ((size_t)b * NN + idx) * 3;
      r0 = rp[0]; r1 = rp[1]; r2 = rp[2];
      const float* tp = trans + ((size_t)b * NN + idx) * 3;
      t0 = tp[0]; t1 = tp[1]; t2 = tp[2];
    }
    const int o = b * MAXD + t;
    out[OFF_BOX + (size_t)o * 4 + 0] = b0;
    out[OFF_BOX + (size_t)o * 4 + 1] = b1;
    out[OFF_BOX + (size_t)o * 4 + 2] = b2;
    out[OFF_BOX + (size_t)o * 4 + 3] = b3;
    out[OFF_SC + o] = os;
    out[OFF_LB + o] = ol;
    out[OFF_RT + (size_t)o * 3 + 0] = r0;
    out[OFF_RT + (size_t)o * 3 + 1] = r1;
    out[OFF_RT + (size_t)o * 3 + 2] = r2;
    out[OFF_TR + (size_t)o * 3 + 0] = t0;
    out[OFF_TR + (size_t)o * 3 + 1] = t1;
    out[OFF_TR + (size_t)o * 3 + 2] = t2;
  }
}

extern "C" void kernel_launch(void* const* d_in, const int* in_sizes, int n_in,
                              void* d_out, int out_size, void* d_ws, size_t ws_size,
                              hipStream_t stream) {
  const float* boxes = (const float*)d_in[0];
  const float* cls   = (const float*)d_in[1];
  const float* rot   = (const float*)d_in[2];
  const float* trans = (const float*)d_in[3];
  float* out = (float*)d_out;

  u16* ord16 = (u16*)d_ws;                             // 32 MB
  int* tidx  = (int*)(ord16 + (size_t)NB * NC * NN);
  float* tsc = (float*)(tidx + NB * NC * KK);
  float* ksc = tsc + NB * NC * KK;

  transpose_kernel<<<NB * 25, 512, 0, stream>>>(cls, ord16);
  select_kernel<<<NB * NC, 512, 0, stream>>>(ord16, cls, tidx, tsc);
  nms_kernel<<<NB * NC / 2, 128, 0, stream>>>(boxes, tidx, tsc, ksc);
  final_kernel<<<NB, 512, 0, stream>>>(boxes, rot, trans, tidx, ksc, out);
}

// Round 7
// 151.961 us; speedup vs baseline: 1.9491x; 1.0600x over previous
//
#include <hip/hip_runtime.h>
#include <math.h>

typedef unsigned int u32;
typedef unsigned long long u64;
typedef unsigned short u16;

constexpr int NB   = 32;     // batch
constexpr int NN   = 50000;  // boxes per image
constexpr int NC   = 10;     // classes
constexpr int KK   = 512;    // PRE_NMS_TOPK
constexpr int MAXD = 100;    // MAX_DETECTIONS
constexpr int CAP  = 2048;   // candidate capacity (expected ~524 with linear digest)
constexpr int CH   = 2000;   // rows per transpose chunk (50000 = 25*2000)

// output section offsets (floats)
constexpr int OFF_BOX = 0;
constexpr int OFF_SC  = NB * MAXD * 4;
constexpr int OFF_LB  = OFF_SC + NB * MAXD;
constexpr int OFF_RT  = OFF_LB + NB * MAXD;
constexpr int OFF_TR  = OFF_RT + NB * MAXD * 3;

__device__ __forceinline__ u32 ord_f32(float s) {
  u32 u = __float_as_uint(s);
  return (u & 0x80000000u) ? ~u : (u | 0x80000000u);
}
__device__ __forceinline__ float unord_f32(u32 o) {
  u32 u = (o & 0x80000000u) ? (o & 0x7FFFFFFFu) : ~o;
  return __uint_as_float(u);
}
// key: high 32 = ordered masked score, low 32 = ~idx (ties -> lower idx wins)
__device__ __forceinline__ u64 make_key(float s, u32 i) {
  float sp = (s > 0.01f) ? s : -INFINITY;
  return ((u64)ord_f32(sp) << 32) | (u64)(u32)(~i);
}
// linear-quantized monotone digest: uniform scores -> uniform bins
__device__ __forceinline__ u16 digest16(float x) {
  if (!(x > 0.01f)) return 0;
  u32 q = (u32)(x * 65536.0f);      // RN mul + trunc cvt: monotone in x
  return (u16)(q > 65535u ? 65535u : q);
}

// ---------- Kernel A: coalesced transpose to 16-bit linear digests ----------
__global__ __launch_bounds__(512) void transpose_kernel(
    const float* __restrict__ cls, u16* __restrict__ ord16) {
  const int blk = blockIdx.x;
  const int b = blk / 25, ch = blk % 25;
  const float* src = cls + ((size_t)b * NN + (size_t)ch * CH) * NC;
  __shared__ u16 tile[CH * 11];  // pad 10->11 to break bank conflicts
  const int t = threadIdx.x;
  for (int q = t; q < CH * NC / 4; q += 512) {
    float4 v = ((const float4*)src)[q];
    float arr[4] = {v.x, v.y, v.z, v.w};
    const int e = q * 4;
#pragma unroll
    for (int k = 0; k < 4; ++k) {
      u16 o = digest16(arr[k]);
      int ee = e + k, r = ee / 10, c = ee - r * 10;
      tile[r * 11 + c] = o;
    }
  }
  __syncthreads();
  for (int q = t; q < CH * NC / 4; q += 512) {
    const int c = q / (CH / 4);
    const int r = (q - c * (CH / 4)) * 4;
    ushort4 o;
    o.x = tile[(r + 0) * 11 + c];
    o.y = tile[(r + 1) * 11 + c];
    o.z = tile[(r + 2) * 11 + c];
    o.w = tile[(r + 3) * 11 + c];
    ((ushort4*)ord16)[((size_t)(b * NC + c) * NN + (size_t)ch * CH + r) >> 2] = o;
  }
}

// ---------- Kernel B: exact top-512 per (b,c): hist + gather + rank-sort ----
__global__ __launch_bounds__(512) void select_kernel(
    const u16* __restrict__ ord16, const float* __restrict__ cls,
    int* __restrict__ out_idx, float* __restrict__ out_sc) {
  const int bc = blockIdx.x;
  const int b = bc / NC, c = bc % NC;
  const u16* col = ord16 + (size_t)bc * NN;
  const float* sbase = cls + (size_t)b * NN * NC + c;
  // bank-transposed 4096-bin histogram: logical bin d at (d&7)*512 + (d>>3).
  // After threshold-find, this 16 KiB is dead and aliased as cand[2048] u64.
  __shared__ __align__(16) u32 hist[4096];
  __shared__ u32 wtot[8], wsuf[8];
  __shared__ u64 sel[KK];
  __shared__ int s_cnt, s_d;
  const int t = threadIdx.x;
  const int lane = t & 63, wv = t >> 6;

  for (int i = t; i < 4096; i += 512) hist[i] = 0;
  if (t == 0) s_cnt = 0;
  __syncthreads();
  // pass 1: 12-bit histogram over the contiguous u16 digest column
  for (int q = t; q < NN / 8; q += 512) {
    uint4 v = ((const uint4*)col)[q];
    u32 w[4] = {v.x, v.y, v.z, v.w};
#pragma unroll
    for (int k = 0; k < 4; ++k) {
      u32 d0 = (w[k] & 0xFFFFu) >> 4;
      u32 d1 = (w[k] >> 16) >> 4;
      atomicAdd(&hist[(d0 & 7u) * 512 + (d0 >> 3)], 1u);
      atomicAdd(&hist[(d1 & 7u) * 512 + (d1 >> 3)], 1u);
    }
  }
  __syncthreads();
  // chunk sums: thread t owns logical bins [8t, 8t+8) at addrs {k*512+t}
  u32 csum = 0;
#pragma unroll
  for (int k = 0; k < 8; ++k) csum += hist[k * 512 + t];
  // wave-internal inclusive suffix scan over thread index (bin-ascending)
  u32 incl = csum;
#pragma unroll
  for (int s = 1; s < 64; s <<= 1) {
    u32 o = __shfl_down(incl, s, 64);
    if (lane + s < 64) incl += o;
  }
  if (lane == 0) wtot[wv] = incl;
  __syncthreads();
  if (t < 8) {
    u32 sum = 0;
    for (int w2 = 7; w2 > t; --w2) sum += wtot[w2];
    wsuf[t] = sum;  // exclusive suffix over wave totals
  }
  __syncthreads();
  const u32 sufChunk = wsuf[wv] + (incl - csum);  // # digests in bins > 8t+7
  // locate threshold bin d*: count(bin > d*) < 512 <= count(bin >= d*)
  if (sufChunk < (u32)KK && sufChunk + csum >= (u32)KK) {
    u32 run = sufChunk;
#pragma unroll
    for (int k = 7; k >= 0; --k) {
      u32 h = hist[k * 512 + t];
      if (run < (u32)KK && run + h >= (u32)KK) s_d = t * 8 + k;
      run += h;
    }
  }
  __syncthreads();
  const u32 dstar = (u32)s_d;
  u64* cand = reinterpret_cast<u64*>(hist);  // hist is dead from here on
  // pass 2: gather exact keys of all digest-bin >= d* candidates (~524)
  for (int q = t; q < NN / 8; q += 512) {
    uint4 v = ((const uint4*)col)[q];
    u32 w[4] = {v.x, v.y, v.z, v.w};
#pragma unroll
    for (int k = 0; k < 8; ++k) {
      u32 dg = (k & 1) ? (w[k >> 1] >> 16) : (w[k >> 1] & 0xFFFFu);
      if ((dg >> 4) >= dstar) {
        u32 i = (u32)(q * 8 + k);
        int p = atomicAdd(&s_cnt, 1);
        if (p < CAP) cand[p] = make_key(sbase[(size_t)i * NC], i);
      }
    }
  }
  __syncthreads();
  const int M = min(s_cnt, CAP);
  // rank-sort: unique u64 keys -> unique ranks; broadcast LDS reads, no barriers
  for (int i = t; i < M; i += 512) {
    const u64 key = cand[i];
    int rank = 0;
    for (int j = 0; j < M; ++j) rank += (cand[j] > key) ? 1 : 0;
    if (rank < KK) sel[rank] = key;
  }
  __syncthreads();
  {
    u64 k = sel[t];
    out_idx[bc * KK + t] = (int)(~(u32)k);
    out_sc[bc * KK + t] = unord_f32((u32)(k >> 32));
  }
}

// ------- Kernel 2: on-demand greedy NMS, one wave per (b,c), 2 per block ----
__global__ __launch_bounds__(128) void nms_kernel(
    const float* __restrict__ boxes, const int* __restrict__ tidx,
    const float* __restrict__ tsc, float* __restrict__ ksc) {
  const int wv = threadIdx.x >> 6;
  const int lane = threadIdx.x & 63;
  const int bc = blockIdx.x * 2 + wv;
  const int b = bc / NC;
  __shared__ float4 bx4[2][KK];
  __shared__ float ars[2][KK];

  float jx1[8], jy1[8], jx2[8], jy2[8], jar[8], jsc[8];
  u64 vw[8], sup[8], kw[8];
#pragma unroll
  for (int q = 0; q < 8; ++q) {
    const int j = q * 64 + lane;
    int idx = tidx[bc * KK + j];
    const float4 bx = *(const float4*)(boxes + ((size_t)b * NN + idx) * 4);
    float ar = (bx.z - bx.x) * (bx.w - bx.y);
    bx4[wv][j] = bx;
    ars[wv][j] = ar;
    jx1[q] = bx.x; jy1[q] = bx.y; jx2[q] = bx.z; jy2[q] = bx.w;
    jar[q] = ar;
    float sc = tsc[bc * KK + j];
    jsc[q] = sc;
    vw[q] = __ballot(sc > 0.01f);
    sup[q] = 0;
    kw[q] = 0;
  }

  // RN32(inter/uni) > 0.5  <=>  inter/uni > 0.5 + 2^-25 (tie->even = 0.5)
  const double C = 0x1.000001p-1;

  int count = 0;
  bool done = false;
#pragma unroll
  for (int w = 0; w < 8; ++w) {
    if (!done) {
      u64 av = vw[w] & ~sup[w];
      while (av) {
        const int bbit = (int)__builtin_ctzll(av);
        const int i = w * 64 + bbit;
        kw[w] |= 1ull << bbit;
        if (++count == MAXD) { done = true; break; }
        const float4 bi = bx4[wv][i];
        const float ai = ars[wv][i];
#pragma unroll
        for (int q = 0; q < 8; ++q) {
          if (q >= w) {
            float ix1 = fmaxf(bi.x, jx1[q]);
            float iy1 = fmaxf(bi.y, jy1[q]);
            float ix2 = fminf(bi.z, jx2[q]);
            float iy2 = fminf(bi.w, jy2[q]);
            float iw = fmaxf(ix2 - ix1, 0.0f);
            float ih = fmaxf(iy2 - iy1, 0.0f);
            float inter = iw * ih;
            float uni = ai + jar[q] - inter;
            bool s = (uni > 0.0f) && (fma(-C, (double)uni, (double)inter) > 0.0);
            sup[q] |= __ballot(s);
          }
        }
        const u64 mask_gt = (bbit == 63) ? 0ull : (~0ull << (bbit + 1));
        av = vw[w] & ~sup[w] & mask_gt;
      }
    }
  }

#pragma unroll
  for (int q = 0; q < 8; ++q) {
    const int j = q * 64 + lane;
    ksc[bc * KK + j] = ((kw[q] >> lane) & 1ull) ? jsc[q] : -INFINITY;
  }
}

// ---------------- Kernel 3: per-image top-100 + gather ----------------
__global__ __launch_bounds__(512) void final_kernel(
    const float* __restrict__ boxes, const float* __restrict__ rot,
    const float* __restrict__ trans, const int* __restrict__ tidx,
    const float* __restrict__ ksc, float* __restrict__ out) {
  const int b = blockIdx.x;
  __shared__ u64 ck[1024];
  __shared__ int cnt;
  const int t = threadIdx.x;
  if (t == 0) cnt = 0;
  __syncthreads();
  for (int j = t; j < NC * KK; j += 512) {
    float s = ksc[b * NC * KK + j];
    if (s != -INFINITY) {
      int p = atomicAdd(&cnt, 1);
      if (p < 1024) ck[p] = ((u64)ord_f32(s) << 32) | (u64)(u32)(~(u32)j);
    }
  }
  __syncthreads();
  const int n = min(cnt, 1024);
  int npow = 128;
  while (npow < n) npow <<= 1;
  for (int i = n + t; i < npow; i += 512) ck[i] = 0;
  __syncthreads();
  bitonic_desc_final: ;
  // descending bitonic sort (inline; small npow)
  for (int k = 2; k <= npow; k <<= 1) {
    for (int j = k >> 1; j > 0; j >>= 1) {
      for (int i = t; i < npow; i += 512) {
        int ixj = i ^ j;
        if (ixj > i) {
          u64 x = ck[i], y = ck[ixj];
          if (((i & k) == 0) ? (x < y) : (x > y)) { ck[i] = y; ck[ixj] = x; }
        }
      }
      __syncthreads();
    }
  }

  if (t < MAXD) {
    float b0 = -1.f, b1 = -1.f, b2 = -1.f, b3 = -1.f;
    float os = -1.f, ol = -1.f;
    float r0 = -1.f, r1 = -1.f, r2 = -1.f;
    float t0 = -1.f, t1 = -1.f, t2 = -1.f;
    if (t < n) {
      u64 k = ck[t];
      int j = (int)(~(u32)k);
      int c = j >> 9, slot = j & (KK - 1);
      int idx = tidx[(b * NC + c) * KK + slot];
      os = unord_f32((u32)(k >> 32));
      ol = (float)c;
      const float4 bx = *(const float4*)(boxes + ((size_t)b * NN + idx) * 4);
      b0 = bx.x; b1 = bx.y; b2 = bx.z; b3 = bx.w;
      const float* rp = rot + ((size_t)b * NN + idx) * 3;
      r0 = rp[0]; r1 = rp[1]; r2 = rp[2];
      const float* tp = trans + ((size_t)b * NN + idx) * 3;
      t0 = tp[0]; t1 = tp[1]; t2 = tp[2];
    }
    const int o = b * MAXD + t;
    out[OFF_BOX + (size_t)o * 4 + 0] = b0;
    out[OFF_BOX + (size_t)o * 4 + 1] = b1;
    out[OFF_BOX + (size_t)o * 4 + 2] = b2;
    out[OFF_BOX + (size_t)o * 4 + 3] = b3;
    out[OFF_SC + o] = os;
    out[OFF_LB + o] = ol;
    out[OFF_RT + (size_t)o * 3 + 0] = r0;
    out[OFF_RT + (size_t)o * 3 + 1] = r1;
    out[OFF_RT + (size_t)o * 3 + 2] = r2;
    out[OFF_TR + (size_t)o * 3 + 0] = t0;
    out[OFF_TR + (size_t)o * 3 + 1] = t1;
    out[OFF_TR + (size_t)o * 3 + 2] = t2;
  }
}

extern "C" void kernel_launch(void* const* d_in, const int* in_sizes, int n_in,
                              void* d_out, int out_size, void* d_ws, size_t ws_size,
                              hipStream_t stream) {
  const float* boxes = (const float*)d_in[0];
  const float* cls   = (const float*)d_in[1];
  const float* rot   = (const float*)d_in[2];
  const float* trans = (const float*)d_in[3];
  float* out = (float*)d_out;

  u16* ord16 = (u16*)d_ws;                             // 32 MB
  int* tidx  = (int*)(ord16 + (size_t)NB * NC * NN);
  float* tsc = (float*)(tidx + NB * NC * KK);
  float* ksc = tsc + NB * NC * KK;

  transpose_kernel<<<NB * 25, 512, 0, stream>>>(cls, ord16);
  select_kernel<<<NB * NC, 512, 0, stream>>>(ord16, cls, tidx, tsc);
  nms_kernel<<<NB * NC / 2, 128, 0, stream>>>(boxes, tidx, tsc, ksc);
  final_kernel<<<NB, 512, 0, stream>>>(boxes, rot, trans, tidx, ksc, out);
}